// Round 1
// 414.455 us; speedup vs baseline: 1.0537x; 1.0537x over previous
//
#include <hip/hip_runtime.h>
#include <math.h>

#define B 64
#define T 4096
#define D 256
#define U 256

typedef __attribute__((ext_vector_type(8)))  short s16x8;
typedef __attribute__((ext_vector_type(16))) float f32x16;

#define MT 32                 // rows per m-step
#define SPB 16                // m-steps per block
#define NBLK ((B*T)/(MT*SPB)) // 512 blocks; 8 blocks per batch b
#define LDAP 33               // padded m-stride (uint4 units) per k8-row

// DPP cross-lane add (VALU pipe, not LDS): v += lane-permuted v
#define DPP_ADD(v, ctrl)                                                     \
  v += __int_as_float(__builtin_amdgcn_update_dpp(                           \
      0, __float_as_int(v), ctrl, 0xF, 0xF, true))

// Accumulate 8 d-elements (one LDS cell hi+lo) scaled by wr into acc[8].
__device__ __forceinline__ void acc8(float* acc, float wr, uint4 h, uint4 l) {
  const unsigned* hw = (const unsigned*)&h;
  const unsigned* lw = (const unsigned*)&l;
#pragma unroll
  for (int jw = 0; jw < 4; ++jw) {
    const float ae = __uint_as_float(hw[jw] << 16) +
                     __uint_as_float(lw[jw] << 16);
    const float ao = __uint_as_float(hw[jw] & 0xffff0000u) +
                     __uint_as_float(lw[jw] & 0xffff0000u);
    acc[2 * jw]     = fmaf(wr, ae, acc[2 * jw]);
    acc[2 * jw + 1] = fmaf(wr, ao, acc[2 * jw + 1]);
  }
}

// ============ fused scores + online context-partial =========================
// s[b,t] = sum_u tanh((A@(W1+W2))[u]) * v[u];  w = e^s  (no max needed:
// |s| <= sum|v| ~ 12.8, e^s fits fp32 easily).  Per step, after the score
// reduce, accumulate ctx_part[d] += w_t * A[t,d] from the LDS tile and a
// per-block Z partial.  attn buffer receives UNNORMALIZED w.
__global__ __launch_bounds__(512, 2) void scores_ctx_kernel(
    const float* __restrict__ A,    // [B*T, D]
    const float* __restrict__ W1,   // [D, U]
    const float* __restrict__ W2,   // [D, U]
    const float* __restrict__ v,    // [U]
    float* __restrict__ w_out,      // [B*T] unnormalized weights e^s
    float* __restrict__ part,       // [NBLK][D] ctx partials (unnormalized)
    float* __restrict__ zpart)      // [NBLK] sum of w over block's 512 tokens
{
  __shared__ uint4 AH[32 * LDAP];   // [k8][m] 8 bf16 hi per cell
  __shared__ uint4 AL[32 * LDAP];   // lo
  __shared__ float red[32][8];      // [row][wave] score partials
  __shared__ float wbuf[32];        // per-step token weights

  const int tid  = threadIdx.x;
  const int lane = tid & 63;
  const int wv   = tid >> 6;        // 0..7
  const int l31  = lane & 31;
  const int half = lane >> 5;

  // ---- register-resident B-fragments from W1+W2 (once per block) ----
  const int n = wv * 32 + l31;
  s16x8 Bh[16], Bl[16];
#pragma unroll
  for (int s = 0; s < 16; ++s) {
    s16x8 bh, bl;
#pragma unroll
    for (int j = 0; j < 8; ++j) {
      const int k = s * 16 + half * 8 + j;
      const float w = W1[k * 256 + n] + W2[k * 256 + n];
      const unsigned int uw = __float_as_uint(w);
      const float wl = w - __uint_as_float(uw & 0xffff0000u);
      bh[j] = (short)(uw >> 16);
      bl[j] = (short)(__float_as_uint(wl) >> 16);
    }
    Bh[s] = bh; Bl[s] = bl;
  }
  const float vv = v[n];

  // staging map: thread -> (row sm, float4-chunk sc0 + 16*i)
  const int sm  = tid >> 4;   // 0..31
  const int sc0 = tid & 15;

  // ctx-accum map: thread -> (d-octet k8c, rows mlc & mlc+16)
  const int k8c = tid >> 4;   // 0..31  (d = k8c*8 + j)
  const int mlc = tid & 15;

  float acc[8] = {0.f, 0.f, 0.f, 0.f, 0.f, 0.f, 0.f, 0.f};
  float zacc = 0.f;

  const size_t row0 = (size_t)blockIdx.x * (MT * SPB);
  float4 rg[4];
  {
    const float4* src = (const float4*)(A + (row0 + sm) * 256);
#pragma unroll
    for (int i = 0; i < 4; ++i) rg[i] = src[sc0 + 16 * i];
  }

  for (int step = 0; step < SPB; ++step) {
    const size_t rowbase = row0 + (size_t)step * MT;

    // ---- convert prefetched tile to hi/lo bf16, write LDS ----
#pragma unroll
    for (int i = 0; i < 4; ++i) {
      const float4 a = rg[i];
      const int k  = 4 * (sc0 + 16 * i);
      const int k8 = k >> 3;
      const int off = (k >> 2) & 1;
      const unsigned int ux = __float_as_uint(a.x), uy = __float_as_uint(a.y);
      const unsigned int uz = __float_as_uint(a.z), uw = __float_as_uint(a.w);
      const uint2 hi2 = make_uint2((ux >> 16) | (uy & 0xffff0000u),
                                   (uz >> 16) | (uw & 0xffff0000u));
      const float lx = a.x - __uint_as_float(ux & 0xffff0000u);
      const float ly = a.y - __uint_as_float(uy & 0xffff0000u);
      const float lz = a.z - __uint_as_float(uz & 0xffff0000u);
      const float lw = a.w - __uint_as_float(uw & 0xffff0000u);
      const uint2 lo2 = make_uint2(
          (__float_as_uint(lx) >> 16) | (__float_as_uint(ly) & 0xffff0000u),
          (__float_as_uint(lz) >> 16) | (__float_as_uint(lw) & 0xffff0000u));
      ((uint2*)&AH[k8 * LDAP + sm])[off] = hi2;
      ((uint2*)&AL[k8 * LDAP + sm])[off] = lo2;
    }
    __syncthreads();                                  // bar A

    // prefetch next tile (latency hidden under MFMA phase)
    if (step + 1 < SPB) {
      const float4* src = (const float4*)(A + (rowbase + MT + sm) * 256);
#pragma unroll
      for (int i = 0; i < 4; ++i) rg[i] = src[sc0 + 16 * i];
    }

    // ---- MFMA: 3-product split-bf16, 3 independent acc chains ----
    f32x16 a0 = {}, a1 = {}, a2 = {};
#pragma unroll
    for (int s = 0; s < 16; ++s) {
      const uint4 qh = AH[(2 * s + half) * LDAP + l31];
      const uint4 ql = AL[(2 * s + half) * LDAP + l31];
      const s16x8 ah = __builtin_bit_cast(s16x8, qh);
      const s16x8 al = __builtin_bit_cast(s16x8, ql);
      a0 = __builtin_amdgcn_mfma_f32_32x32x16_bf16(ah, Bh[s], a0, 0, 0, 0);
      a1 = __builtin_amdgcn_mfma_f32_32x32x16_bf16(ah, Bl[s], a1, 0, 0, 0);
      a2 = __builtin_amdgcn_mfma_f32_32x32x16_bf16(al, Bh[s], a2, 0, 0, 0);
    }

    // ---- epilogue: tanh, *v[u], reduce wave's 32 cols (DPP = VALU pipe) ----
#pragma unroll
    for (int r = 0; r < 16; ++r) {
      const float x = a0[r] + a1[r] + a2[r];
      const float e = __expf(x + x);                     // e^{2x}
      float p = (1.f - 2.f * __builtin_amdgcn_rcpf(e + 1.f)) * vv;  // tanh*v
      DPP_ADD(p, 0xB1);   // + lane^1
      DPP_ADD(p, 0x4E);   // + lane^2
      DPP_ADD(p, 0x141);  // row_half_mirror: 8-sum
      DPP_ADD(p, 0x140);  // row_mirror: 16-sum
      p += __int_as_float(
          __builtin_amdgcn_ds_swizzle(__float_as_int(p), 0x401F));  // xor16
      if (l31 == 0)
        red[(r & 3) + 8 * (r >> 2) + 4 * half][wv] = p;
    }
    __syncthreads();                                  // bar B

    if (tid < 32) {
      const float4* rp = (const float4*)&red[tid][0];
      const float4 ra = rp[0], rb = rp[1];
      const float s =
          ra.x + ra.y + ra.z + ra.w + rb.x + rb.y + rb.z + rb.w;
      const float w = __expf(s);                       // bounded: |s| <= ~13
      w_out[rowbase + tid] = w;
      wbuf[tid] = w;
      zacc += w;
    }
    __syncthreads();                                  // bar C

    // ---- online context accumulate from the LDS tile ----
    {
      const float w0 = wbuf[mlc];
      const float w1 = wbuf[mlc + 16];
      const uint4 h0 = AH[k8c * LDAP + mlc];
      const uint4 l0 = AL[k8c * LDAP + mlc];
      const uint4 h1 = AH[k8c * LDAP + mlc + 16];
      const uint4 l1 = AL[k8c * LDAP + mlc + 16];
      acc8(acc, w0, h0, l0);
      acc8(acc, w1, h1, l1);
    }
    __syncthreads();                                  // bar D (tile reusable)
  }

  // ---- block-level reductions ----
  // acc[j]: sum over the 16 lanes sharing k8c (a 16-lane-aligned group)
  float accsel = 0.f;
#pragma unroll
  for (int j = 0; j < 8; ++j) {
    float p = acc[j];
    DPP_ADD(p, 0xB1);
    DPP_ADD(p, 0x4E);
    DPP_ADD(p, 0x141);
    DPP_ADD(p, 0x140);
    if ((tid & 15) == j) accsel = p;
  }
  if ((tid & 15) < 8)
    part[blockIdx.x * 256 + k8c * 8 + (tid & 15)] = accsel;

  // Z partial: sum zacc over lanes 0..31 of wave 0
  if (tid < 32) {
    float z = zacc;
    DPP_ADD(z, 0xB1);
    DPP_ADD(z, 0x4E);
    DPP_ADD(z, 0x141);
    DPP_ADD(z, 0x140);
    z += __int_as_float(
        __builtin_amdgcn_ds_swizzle(__float_as_int(z), 0x401F));  // xor16
    if (tid == 0) zpart[blockIdx.x] = z;
  }
}

// ============ finalize: Z per batch, scale ctx + attn =======================
__global__ __launch_bounds__(1024) void finalize_kernel(
    const float* __restrict__ part,   // [NBLK][D] = [B*8][D]
    const float* __restrict__ zpart,  // [NBLK]    = [B*8]
    float* __restrict__ attn,         // [B*T] in: w, out: w/Z
    float* __restrict__ ctx)          // [B*D]
{
  const int b = blockIdx.x;
  const int tid = threadIdx.x;
  __shared__ float shinv;
  if (tid == 0) {
    float z = 0.f;
#pragma unroll
    for (int c = 0; c < 8; ++c) z += zpart[b * 8 + c];
    shinv = 1.0f / z;
  }
  __syncthreads();
  const float iz = shinv;

  if (tid < D) {
    float s = 0.f;
#pragma unroll
    for (int c = 0; c < 8; ++c) s += part[(b * 8 + c) * D + tid];
    ctx[b * D + tid] = s * iz;
  }

  float4* row = (float4*)(attn + (long)b * T);
  float4 w4 = row[tid];                 // 1024 threads * 4 = T
  w4.x *= iz; w4.y *= iz; w4.z *= iz; w4.w *= iz;
  row[tid] = w4;
}

extern "C" void kernel_launch(void* const* d_in, const int* in_sizes, int n_in,
                              void* d_out, int out_size, void* d_ws, size_t ws_size,
                              hipStream_t stream) {
    const float* lstm = (const float*)d_in[0];  // [B,T,D]
    const float* W1   = (const float*)d_in[1];  // [D,U]
    const float* W2   = (const float*)d_in[2];  // [D,U]
    const float* v    = (const float*)d_in[3];  // [U,1]

    float* out  = (float*)d_out;
    float* ctx  = out;            // [B*D]
    float* attn = out + B * D;    // [B*T]

    float* part  = (float*)d_ws;          // NBLK*D floats = 512 KB
    float* zpart = part + NBLK * D;       // NBLK floats

    scores_ctx_kernel<<<NBLK, 512, 0, stream>>>(lstm, W1, W2, v, attn, part, zpart);
    finalize_kernel<<<B, 1024, 0, stream>>>(part, zpart, attn, ctx);
}

// Round 2
// 397.049 us; speedup vs baseline: 1.0999x; 1.0438x over previous
//
#include <hip/hip_runtime.h>
#include <math.h>

#define B 64
#define T 4096
#define D 256
#define U 256

typedef __attribute__((ext_vector_type(8)))  short s16x8;
typedef __attribute__((ext_vector_type(16))) float f32x16;

#define MT 32                 // rows per m-step
#define SPB 16                // m-steps per block
#define NBLK ((B*T)/(MT*SPB)) // 512 blocks; 8 blocks per batch b
#define LDAP 33               // padded m-stride (uint4 units) per k8-row

// DPP cross-lane add (VALU pipe, not LDS): v += lane-permuted v
#define DPP_ADD(v, ctrl)                                                     \
  v += __int_as_float(__builtin_amdgcn_update_dpp(                           \
      0, __float_as_int(v), ctrl, 0xF, 0xF, true))

// ============ fused scores + online context-partial =========================
// s[b,t] = sum_u tanh((A@(W1+W2))[u]) * v[u];  w = e^s  (no max needed:
// |s| <= sum|v| ~ 13, e^s fits fp32 easily).
// Per 32-row step: MFMA scores -> every thread recomputes w for ITS staging
// row from the red[][] partials (parallel, no funnel), then accumulates
// ctx_part[d] += w * A[row,d] from the f32 staging REGISTERS (exact, no LDS
// round-trip).  2 barriers per step, same as the unfused kernel.
__global__ __launch_bounds__(512, 2) void scores_ctx_kernel(
    const float* __restrict__ A,    // [B*T, D]
    const float* __restrict__ W1,   // [D, U]
    const float* __restrict__ W2,   // [D, U]
    const float* __restrict__ v,    // [U]
    float* __restrict__ w_out,      // [B*T] unnormalized weights e^s
    float* __restrict__ part,       // [NBLK][D] ctx partials (unnormalized)
    float* __restrict__ zpart)      // [NBLK] sum of w over block's 512 tokens
{
  __shared__ uint4 AH[32 * LDAP];   // [k8][m] 8 bf16 hi per cell
  __shared__ uint4 AL[32 * LDAP];   // lo
  __shared__ float red[32][8];      // [row][wave] score partials
  __shared__ float wavebuf[8][16][16]; // block-end ctx reduction
  __shared__ float zred[8];

  const int tid  = threadIdx.x;
  const int lane = tid & 63;
  const int wv   = tid >> 6;        // 0..7
  const int l31  = lane & 31;
  const int half = lane >> 5;

  // ---- register-resident B-fragments from W1+W2 (once per block) ----
  const int n = wv * 32 + l31;
  s16x8 Bh[16], Bl[16];
#pragma unroll
  for (int s = 0; s < 16; ++s) {
    s16x8 bh, bl;
#pragma unroll
    for (int j = 0; j < 8; ++j) {
      const int k = s * 16 + half * 8 + j;
      const float w = W1[k * 256 + n] + W2[k * 256 + n];
      const unsigned int uw = __float_as_uint(w);
      const float wl = w - __uint_as_float(uw & 0xffff0000u);
      bh[j] = (short)(uw >> 16);
      bl[j] = (short)(__float_as_uint(wl) >> 16);
    }
    Bh[s] = bh; Bl[s] = bl;
  }
  const float vv = v[n];

  // staging map: thread -> (row sm, float4-chunk sc0 + 16*i)
  const int sm  = tid >> 4;   // 0..31
  const int sc0 = tid & 15;

  float acc[16];
#pragma unroll
  for (int q = 0; q < 16; ++q) acc[q] = 0.f;
  float zacc = 0.f;

  const size_t row0 = (size_t)blockIdx.x * (MT * SPB);
  float4 rg[4];
  {
    const float4* src = (const float4*)(A + (row0 + sm) * 256);
#pragma unroll
    for (int i = 0; i < 4; ++i) rg[i] = src[sc0 + 16 * i];
  }

  for (int step = 0; step < SPB; ++step) {
    const size_t rowbase = row0 + (size_t)step * MT;

    // ---- convert prefetched tile to hi/lo bf16, write LDS ----
#pragma unroll
    for (int i = 0; i < 4; ++i) {
      const float4 a = rg[i];
      const int k  = 4 * (sc0 + 16 * i);
      const int k8 = k >> 3;
      const int off = (k >> 2) & 1;
      const unsigned int ux = __float_as_uint(a.x), uy = __float_as_uint(a.y);
      const unsigned int uz = __float_as_uint(a.z), uw = __float_as_uint(a.w);
      const uint2 hi2 = make_uint2((ux >> 16) | (uy & 0xffff0000u),
                                   (uz >> 16) | (uw & 0xffff0000u));
      const float lx = a.x - __uint_as_float(ux & 0xffff0000u);
      const float ly = a.y - __uint_as_float(uy & 0xffff0000u);
      const float lz = a.z - __uint_as_float(uz & 0xffff0000u);
      const float lw = a.w - __uint_as_float(uw & 0xffff0000u);
      const uint2 lo2 = make_uint2(
          (__float_as_uint(lx) >> 16) | (__float_as_uint(ly) & 0xffff0000u),
          (__float_as_uint(lz) >> 16) | (__float_as_uint(lw) & 0xffff0000u));
      ((uint2*)&AH[k8 * LDAP + sm])[off] = hi2;
      ((uint2*)&AL[k8 * LDAP + sm])[off] = lo2;
    }
    __syncthreads();                                  // bar A

    // keep this step's rows in registers for the ctx accumulate
    float4 rgc[4];
#pragma unroll
    for (int i = 0; i < 4; ++i) rgc[i] = rg[i];

    // prefetch next tile (latency hidden under MFMA phase)
    if (step + 1 < SPB) {
      const float4* src = (const float4*)(A + (rowbase + MT + sm) * 256);
#pragma unroll
      for (int i = 0; i < 4; ++i) rg[i] = src[sc0 + 16 * i];
    }

    // ---- MFMA: split-bf16, 2 acc chains (a0 = ah*Bh; a1 = ah*Bl + al*Bh) ----
    f32x16 a0 = {}, a1 = {};
#pragma unroll
    for (int s = 0; s < 16; ++s) {
      const uint4 qh = AH[(2 * s + half) * LDAP + l31];
      const uint4 ql = AL[(2 * s + half) * LDAP + l31];
      const s16x8 ah = __builtin_bit_cast(s16x8, qh);
      const s16x8 al = __builtin_bit_cast(s16x8, ql);
      a0 = __builtin_amdgcn_mfma_f32_32x32x16_bf16(ah, Bh[s], a0, 0, 0, 0);
      a1 = __builtin_amdgcn_mfma_f32_32x32x16_bf16(ah, Bl[s], a1, 0, 0, 0);
      a1 = __builtin_amdgcn_mfma_f32_32x32x16_bf16(al, Bh[s], a1, 0, 0, 0);
    }

    // ---- epilogue: tanh, *v[u], reduce wave's 32 cols (DPP = VALU pipe) ----
#pragma unroll
    for (int r = 0; r < 16; ++r) {
      const float x = a0[r] + a1[r];
      const float e = __expf(x + x);                     // e^{2x}
      float p = (1.f - 2.f * __builtin_amdgcn_rcpf(e + 1.f)) * vv;  // tanh*v
      DPP_ADD(p, 0xB1);   // + lane^1
      DPP_ADD(p, 0x4E);   // + lane^2
      DPP_ADD(p, 0x141);  // row_half_mirror: 8-sum
      DPP_ADD(p, 0x140);  // row_mirror: 16-sum
      p += __int_as_float(
          __builtin_amdgcn_ds_swizzle(__float_as_int(p), 0x401F));  // xor16
      if (l31 == 0)
        red[(r & 3) + 8 * (r >> 2) + 4 * half][wv] = p;
    }
    __syncthreads();                                  // bar B

    // ---- every thread: w for its staging row; ctx accumulate from regs ----
    {
      const float4* rp = (const float4*)&red[sm][0];
      const float4 ra = rp[0], rb = rp[1];
      const float s8 =
          ra.x + ra.y + ra.z + ra.w + rb.x + rb.y + rb.z + rb.w;
      const float w = __expf(s8);                      // bounded: |s| <= ~13
      if (sc0 == 0) {
        w_out[rowbase + sm] = w;
        zacc += w;
      }
#pragma unroll
      for (int i = 0; i < 4; ++i) {
        acc[4 * i + 0] = fmaf(w, rgc[i].x, acc[4 * i + 0]);
        acc[4 * i + 1] = fmaf(w, rgc[i].y, acc[4 * i + 1]);
        acc[4 * i + 2] = fmaf(w, rgc[i].z, acc[4 * i + 2]);
        acc[4 * i + 3] = fmaf(w, rgc[i].w, acc[4 * i + 3]);
      }
    }
    // no trailing barrier: next step's LDS writes are ordered by bar A,
    // and red[] rewrites are ordered by bar A as well.
  }

  // ---- block-end reductions ----
  // rows within a wave: lanes lane^16, lane^32 share sc0 (4 sm values/wave)
#pragma unroll
  for (int q = 0; q < 16; ++q) {
    float p = acc[q];
    p += __shfl_xor(p, 16);
    p += __shfl_xor(p, 32);
    acc[q] = p;
  }
  if (lane < 16) {
#pragma unroll
    for (int q = 0; q < 16; ++q) wavebuf[wv][lane][q] = acc[q];
  }
  {
    float z = zacc;                    // nonzero only where sc0==0
    z += __shfl_xor(z, 16);
    z += __shfl_xor(z, 32);
    if (lane == 0) zred[wv] = z;       // wave's 4-row z partial
  }
  __syncthreads();

  if (tid < 256) {
    // d = tid:  sc0 = (d&63)>>2, q = 4*(d>>6) + (d&3)
    const int sc = (tid & 63) >> 2;
    const int q  = 4 * (tid >> 6) + (tid & 3);
    float ssum = 0.f;
#pragma unroll
    for (int wvi = 0; wvi < 8; ++wvi) ssum += wavebuf[wvi][sc][q];
    part[blockIdx.x * 256 + tid] = ssum;
  }
  if (tid == 0) {
    float zz = 0.f;
#pragma unroll
    for (int i = 0; i < 8; ++i) zz += zred[i];
    zpart[blockIdx.x] = zz;
  }
}

// ============ finalize: Z per batch, scale ctx + attn =======================
__global__ __launch_bounds__(1024) void finalize_kernel(
    const float* __restrict__ part,   // [NBLK][D] = [B*8][D]
    const float* __restrict__ zpart,  // [NBLK]    = [B*8]
    float* __restrict__ attn,         // [B*T] in: w, out: w/Z
    float* __restrict__ ctx)          // [B*D]
{
  const int b = blockIdx.x;
  const int tid = threadIdx.x;
  __shared__ float shinv;
  if (tid == 0) {
    float z = 0.f;
#pragma unroll
    for (int c = 0; c < 8; ++c) z += zpart[b * 8 + c];
    shinv = 1.0f / z;
  }
  __syncthreads();
  const float iz = shinv;

  if (tid < D) {
    float s = 0.f;
#pragma unroll
    for (int c = 0; c < 8; ++c) s += part[(b * 8 + c) * D + tid];
    ctx[b * D + tid] = s * iz;
  }

  float4* row = (float4*)(attn + (long)b * T);
  float4 w4 = row[tid];                 // 1024 threads * 4 = T
  w4.x *= iz; w4.y *= iz; w4.z *= iz; w4.w *= iz;
  row[tid] = w4;
}

extern "C" void kernel_launch(void* const* d_in, const int* in_sizes, int n_in,
                              void* d_out, int out_size, void* d_ws, size_t ws_size,
                              hipStream_t stream) {
    const float* lstm = (const float*)d_in[0];  // [B,T,D]
    const float* W1   = (const float*)d_in[1];  // [D,U]
    const float* W2   = (const float*)d_in[2];  // [D,U]
    const float* v    = (const float*)d_in[3];  // [U,1]

    float* out  = (float*)d_out;
    float* ctx  = out;            // [B*D]
    float* attn = out + B * D;    // [B*T]

    float* part  = (float*)d_ws;          // NBLK*D floats = 512 KB
    float* zpart = part + NBLK * D;       // NBLK floats

    scores_ctx_kernel<<<NBLK, 512, 0, stream>>>(lstm, W1, W2, v, attn, part, zpart);
    finalize_kernel<<<B, 1024, 0, stream>>>(part, zpart, attn, ctx);
}